// Round 2
// baseline (274.175 us; speedup 1.0000x reference)
//
#include <hip/hip_runtime.h>
#include <stdint.h>

#define N_ROWS 8192
#define H_DIM  1024
#define I_DIM  4096

typedef unsigned short u16;
typedef __bf16 bf16x8 __attribute__((ext_vector_type(8)));
typedef float f32x4 __attribute__((ext_vector_type(4)));
typedef u16 u16x4 __attribute__((ext_vector_type(4)));

__device__ __forceinline__ u16 f2bf(float f) {
    union { float f; uint32_t u; } v; v.f = f;
    uint32_t u = v.u;
    u += 0x7FFFu + ((u >> 16) & 1u);   // RNE
    return (u16)(u >> 16);
}

__device__ __forceinline__ float bf2f(u16 h) {
    union { uint32_t u; float f; } v; v.u = ((uint32_t)h) << 16;
    return v.f;
}

__device__ __forceinline__ float gelu_tanh(float x) {
    float u = 0.7978845608028654f * (x + 0.044715f * x * x * x);
    u = fminf(fmaxf(u, -15.f), 15.f);
    float e = __expf(2.f * u);
    float t = (e - 1.f) / (e + 1.f);
    return 0.5f * x * (1.f + t);
}

// ---- global -> LDS direct (16B per lane) ----
__device__ __forceinline__ void load_lds16(const void* g, void* l) {
    auto gp = reinterpret_cast<const __attribute__((address_space(1))) uint32_t*>(
        reinterpret_cast<uintptr_t>(g));
    auto lp = reinterpret_cast<__attribute__((address_space(3))) uint32_t*>(
        static_cast<uint32_t>(reinterpret_cast<uintptr_t>(l)));
    __builtin_amdgcn_global_load_lds(gp, lp, 16, 0, 0);
}

// Stage a 128x32 bf16 tile (rows row0.., k-cols k0..k0+32) from row-major src
// (stride elems) into LDS tile (linear dest, XOR-swizzled global source so that
// LDS[r][slot s] holds global k-slot s^(r&3); reads undo the XOR).
__device__ __forceinline__ void stage_tile(const u16* __restrict__ src, int stride,
                                           int row0, int k0, u16* lds, int t) {
#pragma unroll
    for (int i = 0; i < 2; ++i) {
        int r = i * 64 + (t >> 2);
        int s = t & 3;
        int ss = s ^ (r & 3);
        const u16* g = src + (size_t)(row0 + r) * stride + k0 + ss * 8;
        load_lds16(g, lds + i * 2048 + t * 8);
    }
}

__device__ __forceinline__ bf16x8 ld_frag(const u16* lds, int row, int g) {
    int slot = g ^ (row & 3);
    return *reinterpret_cast<const bf16x8*>(lds + row * 32 + slot * 8);
}

// ---- GEMM1: hid = gelu(xln·W1g^T + bg) * (xln·W1l^T + bl), bf16 out ----
__global__ __launch_bounds__(256, 2) void gemm1_gated(
    const u16* __restrict__ A, const u16* __restrict__ W,
    const float* __restrict__ bias, u16* __restrict__ hid)
{
    __shared__ u16 As[2][128 * 32];
    __shared__ u16 Bg[2][128 * 32];
    __shared__ u16 Bl[2][128 * 32];
    const int t = threadIdx.x;
    const int lane = t & 63, wid = t >> 6;
    const int wm = wid >> 1, wn = wid & 1;
    const int row0 = blockIdx.y * 128, c0 = blockIdx.x * 128;
    const int g = lane >> 4, r16 = lane & 15;

    f32x4 accg[4][4] = {};
    f32x4 accl[4][4] = {};

    stage_tile(A, H_DIM, row0, 0, As[0], t);
    stage_tile(W, H_DIM, c0, 0, Bg[0], t);
    stage_tile(W, H_DIM, I_DIM + c0, 0, Bl[0], t);

    const int NT = H_DIM / 32;
    for (int kt = 0; kt < NT; ++kt) {
        const int cur = kt & 1;
        __syncthreads();
        if (kt + 1 < NT) {
            const int k0 = (kt + 1) * 32;
            stage_tile(A, H_DIM, row0, k0, As[cur ^ 1], t);
            stage_tile(W, H_DIM, c0, k0, Bg[cur ^ 1], t);
            stage_tile(W, H_DIM, I_DIM + c0, k0, Bl[cur ^ 1], t);
        }
        bf16x8 af[4], bgf[4], blf[4];
#pragma unroll
        for (int m = 0; m < 4; ++m) af[m] = ld_frag(As[cur], wm * 64 + m * 16 + r16, g);
#pragma unroll
        for (int n = 0; n < 4; ++n) {
            bgf[n] = ld_frag(Bg[cur], wn * 64 + n * 16 + r16, g);
            blf[n] = ld_frag(Bl[cur], wn * 64 + n * 16 + r16, g);
        }
#pragma unroll
        for (int m = 0; m < 4; ++m)
#pragma unroll
            for (int n = 0; n < 4; ++n) {
                accg[m][n] = __builtin_amdgcn_mfma_f32_16x16x32_bf16(af[m], bgf[n], accg[m][n], 0, 0, 0);
                accl[m][n] = __builtin_amdgcn_mfma_f32_16x16x32_bf16(af[m], blf[n], accl[m][n], 0, 0, 0);
            }
    }

#pragma unroll
    for (int m = 0; m < 4; ++m)
#pragma unroll
        for (int n = 0; n < 4; ++n) {
            const int cg = c0 + wn * 64 + n * 16 + r16;
            const float bgv = bias[cg], blv = bias[I_DIM + cg];
#pragma unroll
            for (int r = 0; r < 4; ++r) {
                const int row = row0 + wm * 64 + m * 16 + g * 4 + r;
                float gate = accg[m][n][r] + bgv;
                float lin  = accl[m][n][r] + blv;
                hid[(size_t)row * I_DIM + cg] = f2bf(gelu_tanh(gate) * lin);
            }
        }
}

// ---- GEMM2: opb = hid·W2^T + b2 (bf16 out) ----
__global__ __launch_bounds__(256, 2) void gemm2_k(
    const u16* __restrict__ A, const u16* __restrict__ W,
    const float* __restrict__ bias, u16* __restrict__ opb)
{
    __shared__ u16 As[2][128 * 32];
    __shared__ u16 Bs[2][128 * 32];
    const int t = threadIdx.x;
    const int lane = t & 63, wid = t >> 6;
    const int wm = wid >> 1, wn = wid & 1;
    const int row0 = blockIdx.y * 128, c0 = blockIdx.x * 128;
    const int g = lane >> 4, r16 = lane & 15;

    f32x4 acc[4][4] = {};

    stage_tile(A, I_DIM, row0, 0, As[0], t);
    stage_tile(W, I_DIM, c0, 0, Bs[0], t);

    const int NT = I_DIM / 32;
    for (int kt = 0; kt < NT; ++kt) {
        const int cur = kt & 1;
        __syncthreads();
        if (kt + 1 < NT) {
            const int k0 = (kt + 1) * 32;
            stage_tile(A, I_DIM, row0, k0, As[cur ^ 1], t);
            stage_tile(W, I_DIM, c0, k0, Bs[cur ^ 1], t);
        }
        bf16x8 af[4], bf[4];
#pragma unroll
        for (int m = 0; m < 4; ++m) af[m] = ld_frag(As[cur], wm * 64 + m * 16 + r16, g);
#pragma unroll
        for (int n = 0; n < 4; ++n) bf[n] = ld_frag(Bs[cur], wn * 64 + n * 16 + r16, g);
#pragma unroll
        for (int m = 0; m < 4; ++m)
#pragma unroll
            for (int n = 0; n < 4; ++n)
                acc[m][n] = __builtin_amdgcn_mfma_f32_16x16x32_bf16(af[m], bf[n], acc[m][n], 0, 0, 0);
    }

#pragma unroll
    for (int m = 0; m < 4; ++m)
#pragma unroll
        for (int n = 0; n < 4; ++n) {
            const int cg = c0 + wn * 64 + n * 16 + r16;
            const float bv = bias[cg];
#pragma unroll
            for (int r = 0; r < 4; ++r) {
                const int row = row0 + wm * 64 + m * 16 + g * 4 + r;
                opb[(size_t)row * H_DIM + cg] = f2bf(acc[m][n][r] + bv);
            }
        }
}

// ---- block mean/var over one row of 1024 (256 threads x 4 elems) ----
__device__ __forceinline__ void block_mean_var(float s, float s2, float* red, int t,
                                               float& mu, float& var) {
#pragma unroll
    for (int off = 32; off > 0; off >>= 1) {
        s  += __shfl_down(s, off);
        s2 += __shfl_down(s2, off);
    }
    const int wid = t >> 6;
    if ((t & 63) == 0) { red[wid] = s; red[4 + wid] = s2; }
    __syncthreads();
    if (t == 0) {
        float a = red[0] + red[1] + red[2] + red[3];
        float b = red[4] + red[5] + red[6] + red[7];
        red[0] = a * (1.f / H_DIM);
        red[1] = b * (1.f / H_DIM);
    }
    __syncthreads();
    mu = red[0];
    var = red[1] - mu * mu;
}

__global__ void ln_pre(const float* __restrict__ x, const float* __restrict__ w,
                       const float* __restrict__ b, u16* __restrict__ xln)
{
    __shared__ float red[8];
    const int row = blockIdx.x, t = threadIdx.x;
    const float4 v = reinterpret_cast<const float4*>(x + (size_t)row * H_DIM)[t];
    float mu, var;
    block_mean_var(v.x + v.y + v.z + v.w,
                   v.x * v.x + v.y * v.y + v.z * v.z + v.w * v.w, red, t, mu, var);
    const float rstd = rsqrtf(var + 1e-5f);
    const float4 wv = reinterpret_cast<const float4*>(w)[t];
    const float4 bv = reinterpret_cast<const float4*>(b)[t];
    u16x4 o;
    o.x = f2bf((v.x - mu) * rstd * wv.x + bv.x);
    o.y = f2bf((v.y - mu) * rstd * wv.y + bv.y);
    o.z = f2bf((v.z - mu) * rstd * wv.z + bv.z);
    o.w = f2bf((v.w - mu) * rstd * wv.w + bv.w);
    reinterpret_cast<u16x4*>(xln + (size_t)row * H_DIM)[t] = o;
}

// post-LN over bf16 'op' rows + fp32 residual add
__global__ void ln_post_res(const u16* __restrict__ op, const float* __restrict__ w,
                            const float* __restrict__ b, const float* __restrict__ x,
                            float* __restrict__ out)
{
    __shared__ float red[8];
    const int row = blockIdx.x, t = threadIdx.x;
    const u16x4 hv = reinterpret_cast<const u16x4*>(op + (size_t)row * H_DIM)[t];
    float4 v;
    v.x = bf2f(hv.x); v.y = bf2f(hv.y); v.z = bf2f(hv.z); v.w = bf2f(hv.w);
    float mu, var;
    block_mean_var(v.x + v.y + v.z + v.w,
                   v.x * v.x + v.y * v.y + v.z * v.z + v.w * v.w, red, t, mu, var);
    const float rstd = rsqrtf(var + 1e-5f);
    const float4 wv = reinterpret_cast<const float4*>(w)[t];
    const float4 bv = reinterpret_cast<const float4*>(b)[t];
    const float4 xv = reinterpret_cast<const float4*>(x + (size_t)row * H_DIM)[t];
    float4 o;
    o.x = (v.x - mu) * rstd * wv.x + bv.x + xv.x;
    o.y = (v.y - mu) * rstd * wv.y + bv.y + xv.y;
    o.z = (v.z - mu) * rstd * wv.z + bv.z + xv.z;
    o.w = (v.w - mu) * rstd * wv.w + bv.w + xv.w;
    reinterpret_cast<float4*>(out + (size_t)row * H_DIM)[t] = o;
}

__global__ void cvt_bf16(const float* __restrict__ in, u16* __restrict__ out, int n4) {
    int i = blockIdx.x * blockDim.x + threadIdx.x;
    if (i >= n4) return;
    float4 v = reinterpret_cast<const float4*>(in)[i];
    u16x4 o = { f2bf(v.x), f2bf(v.y), f2bf(v.z), f2bf(v.w) };
    reinterpret_cast<u16x4*>(out)[i] = o;
}

extern "C" void kernel_launch(void* const* d_in, const int* in_sizes, int n_in,
                              void* d_out, int out_size, void* d_ws, size_t ws_size,
                              hipStream_t stream)
{
    const float* x   = (const float*)d_in[0];
    const float* lnw = (const float*)d_in[1];
    const float* lnb = (const float*)d_in[2];
    const float* w1  = (const float*)d_in[3];
    const float* b1  = (const float*)d_in[4];
    const float* w2  = (const float*)d_in[5];
    const float* b2  = (const float*)d_in[6];
    const float* pw  = (const float*)d_in[7];
    const float* pb  = (const float*)d_in[8];
    float* out = (float*)d_out;

    // Workspace layout (peak 96 MiB), liveness-based aliasing:
    //   [0,16M)   xln   (live: ln_pre -> gemm1)
    //   [16,32M)  w1b   (live: cvt -> gemm1)
    //   [32,96M)  hid   (live: gemm1 -> gemm2)
    //   [0,8M)    w2b   (converted AFTER gemm1, over dead xln)
    //   [8,24M)   opb   (bf16, gemm2 out, over dead xln tail + w1b head)
    char* ws = (char*)d_ws;
    u16* xln = (u16*)(ws);
    u16* w1b = (u16*)(ws + (16u << 20));
    u16* hid = (u16*)(ws + (32u << 20));
    u16* w2b = (u16*)(ws);
    u16* opb = (u16*)(ws + (8u << 20));

    cvt_bf16<<<(2 * I_DIM * H_DIM / 4 + 255) / 256, 256, 0, stream>>>(w1, w1b, 2 * I_DIM * H_DIM / 4);
    ln_pre<<<N_ROWS, 256, 0, stream>>>(x, lnw, lnb, xln);
    gemm1_gated<<<dim3(I_DIM / 128, N_ROWS / 128), 256, 0, stream>>>(xln, w1b, b1, hid);
    cvt_bf16<<<(H_DIM * I_DIM / 4 + 255) / 256, 256, 0, stream>>>(w2, w2b, H_DIM * I_DIM / 4);
    gemm2_k<<<dim3(H_DIM / 128, N_ROWS / 128), 256, 0, stream>>>(hid, w2b, b2, opb);
    ln_post_res<<<N_ROWS, 256, 0, stream>>>(opb, pw, pb, x, out);
}